// Round 1
// 1619.335 us; speedup vs baseline: 1.1483x; 1.1483x over previous
//
#include <hip/hip_runtime.h>

// ---------------------------------------------------------------------------
// GPT-2-like forward, MI355X gfx950. bf16 MFMA for all matmuls, fp32 residual.
// Model dims (fixed by the problem):
#define BB   2
#define SS   2048
#define DD   256
#define HH   4
#define LL   4
#define VV   50257
#define HDIM 64
#define DFF  1024
#define BS   (BB*SS)   // 4096 rows in the token dimension
#define QKVS 768       // fused QKV row width

typedef unsigned short u16;
typedef unsigned int   u32;
typedef __attribute__((ext_vector_type(8))) short bf16x8;   // 8 bf16 in 4 VGPRs
typedef __attribute__((ext_vector_type(4))) float f32x4;

#define DEV static __device__ __forceinline__

DEV u16 f2bf(float f) {            // fp32 -> bf16 bits, round-nearest-even
    u32 x = __builtin_bit_cast(u32, f);
    x += 0x7fffu + ((x >> 16) & 1u);
    return (u16)(x >> 16);
}

DEV f32x4 zero4() { f32x4 v; v[0]=0.f; v[1]=0.f; v[2]=0.f; v[3]=0.f; return v; }

// ---------------------------------------------------------------------------
// fp32 -> bf16 bulk convert (tok_emb for the tied lm_head B operand)
__global__ __launch_bounds__(256) void cvt_kernel(const float* __restrict__ in,
                                                  u16* __restrict__ out, int n4) {
    int i = blockIdx.x * 256 + threadIdx.x;
    if (i >= n4) return;
    float4 v = ((const float4*)in)[i];
    ushort4 o; o.x = f2bf(v.x); o.y = f2bf(v.y); o.z = f2bf(v.z); o.w = f2bf(v.w);
    ((ushort4*)out)[i] = o;
}

// fp32 (K x N) -> bf16 transposed (N x K), one layer per blockIdx.z.
// out is pre-offset to the segment base; outLS is the per-layer stride of out.
__global__ __launch_bounds__(256) void wtrans_kernel(const float* __restrict__ in,
                                                     u16* __restrict__ out, int K, int N,
                                                     size_t outLS) {
    __shared__ float tile[32][33];
    in  += (size_t)blockIdx.z * K * N;
    out += (size_t)blockIdx.z * outLS;
    int tx = threadIdx.x, ty = threadIdx.y;          // block (32,8)
    int n0 = blockIdx.x * 32, k0 = blockIdx.y * 32;
    #pragma unroll
    for (int i = 0; i < 4; i++)
        tile[ty + 8*i][tx] = in[(size_t)(k0 + ty + 8*i) * N + n0 + tx];
    __syncthreads();
    #pragma unroll
    for (int i = 0; i < 4; i++)
        out[(size_t)(n0 + ty + 8*i) * K + k0 + tx] = f2bf(tile[tx][ty + 8*i]);
}

// concat per-layer biases bq|bk|bv (L,256 each) -> (L,768)
__global__ __launch_bounds__(256) void bias_concat(const float* __restrict__ bq,
                                                   const float* __restrict__ bk,
                                                   const float* __restrict__ bv,
                                                   float* __restrict__ out) {
    int i = blockIdx.x * 256 + threadIdx.x;
    if (i >= LL * QKVS) return;
    int l = i / QKVS, c = i - l * QKVS;
    float v;
    if (c < DD)           v = bq[l * DD + c];
    else if (c < 2 * DD)  v = bk[l * DD + c - DD];
    else                  v = bv[l * DD + c - 2 * DD];
    out[i] = v;
}

// ---------------------------------------------------------------------------
// h[b,s,:] = tok_emb[ids[b,s],:] + pos_emb[s,:]   (fp32 residual stream)
__global__ __launch_bounds__(256) void embed_kernel(const int* __restrict__ ids,
                                                    const float* __restrict__ te,
                                                    const float* __restrict__ pe,
                                                    float* __restrict__ h) {
    int i  = blockIdx.x * 256 + threadIdx.x;   // one float4 chunk
    int bs = i >> 6, c = i & 63;               // D/4 = 64 chunks per row
    int id = ids[bs];
    int sr = bs & (SS - 1);
    float4 t = ((const float4*)(te + (size_t)id * DD))[c];
    float4 p = ((const float4*)(pe + (size_t)sr * DD))[c];
    float4 r; r.x = t.x + p.x; r.y = t.y + p.y; r.z = t.z + p.z; r.w = t.w + p.w;
    ((float4*)h)[i] = r;
}

// ---------------------------------------------------------------------------
// LayerNorm: fp32 in -> bf16 out. One wave per row (D=256, 4 floats/lane).
__global__ __launch_bounds__(256) void ln_kernel(const float* __restrict__ x,
                                                 const float* __restrict__ g,
                                                 const float* __restrict__ b,
                                                 u16* __restrict__ out) {
    const int wid = threadIdx.x >> 6, lane = threadIdx.x & 63;
    const int row = blockIdx.x * 4 + wid;
    const float4 v = ((const float4*)(x + (size_t)row * DD))[lane];
    float s = v.x + v.y + v.z + v.w;
    float q = v.x*v.x + v.y*v.y + v.z*v.z + v.w*v.w;
    #pragma unroll
    for (int m = 1; m < 64; m <<= 1) { s += __shfl_xor(s, m); q += __shfl_xor(q, m); }
    const float mean = s * (1.f / DD);
    const float var  = q * (1.f / DD) - mean * mean;
    const float rs   = rsqrtf(var + 1e-5f);
    const float4 gg = ((const float4*)g)[lane];
    const float4 bb = ((const float4*)b)[lane];
    ushort4 o;
    o.x = f2bf((v.x - mean) * rs * gg.x + bb.x);
    o.y = f2bf((v.y - mean) * rs * gg.y + bb.y);
    o.z = f2bf((v.z - mean) * rs * gg.z + bb.z);
    o.w = f2bf((v.w - mean) * rs * gg.w + bb.w);
    ((ushort4*)(out + (size_t)row * DD))[lane] = o;
}

// ---------------------------------------------------------------------------
// Tiled bf16 MFMA GEMM: C(M,N) = A(M,K) @ Bt(N,K)^T  [Bt stored N-major]
// EPI: 0 = +bias -> bf16 ; 1 = gelu(+bias) -> bf16 ;
//      2 = +bias +res -> fp32 ; 3 = plain -> fp32 with N bounds guard (lm_head)
template<int BM, int BN, int EPI>
__global__ __launch_bounds__(256) void gemm_kernel(const u16* __restrict__ A,
                                                   const u16* __restrict__ Bt,
                                                   const float* __restrict__ bias,
                                                   const float* res, void* outp,
                                                   int M, int N, int K) {
    constexpr int NI = BM / 32, NJ = BN / 32;    // 16x16 MFMA tiles per wave dim
    __shared__ __align__(16) u16 As[BM * 72];    // pad 64->72: 2-way bank (free)
    __shared__ __align__(16) u16 Bs[BN * 72];
    const int tid = threadIdx.x;
    const int wid = tid >> 6, lane = tid & 63, quad = lane >> 4, l16 = lane & 15;
    const int m0 = blockIdx.y * BM, n0 = blockIdx.x * BN;
    const int wm = (wid >> 1) * (BM / 2), wn = (wid & 1) * (BN / 2);

    f32x4 acc[NI][NJ];
    #pragma unroll
    for (int i = 0; i < NI; i++)
        #pragma unroll
        for (int j = 0; j < NJ; j++) acc[i][j] = zero4();

    for (int k0 = 0; k0 < K; k0 += 64) {
        #pragma unroll
        for (int p = 0; p < BM / 32; p++) {
            int idx = p * 256 + tid, row = idx >> 3, c = (idx & 7) * 8;
            *(uint4*)(&As[row * 72 + c]) =
                *(const uint4*)(A + (size_t)(m0 + row) * K + k0 + c);
        }
        #pragma unroll
        for (int p = 0; p < BN / 32; p++) {
            int idx = p * 256 + tid, row = idx >> 3, c = (idx & 7) * 8;
            uint4 val{0, 0, 0, 0};
            if (EPI != 3 || (n0 + row) < N)
                val = *(const uint4*)(Bt + (size_t)(n0 + row) * K + k0 + c);
            *(uint4*)(&Bs[row * 72 + c]) = val;
        }
        __syncthreads();
        #pragma unroll
        for (int ks = 0; ks < 2; ks++) {
            bf16x8 af[NI], bfr[NJ];
            #pragma unroll
            for (int i = 0; i < NI; i++)
                af[i] = *(const bf16x8*)(&As[(wm + i*16 + l16) * 72 + ks*32 + quad*8]);
            #pragma unroll
            for (int j = 0; j < NJ; j++)
                bfr[j] = *(const bf16x8*)(&Bs[(wn + j*16 + l16) * 72 + ks*32 + quad*8]);
            #pragma unroll
            for (int i = 0; i < NI; i++)
                #pragma unroll
                for (int j = 0; j < NJ; j++)
                    acc[i][j] = __builtin_amdgcn_mfma_f32_16x16x32_bf16(
                        af[i], bfr[j], acc[i][j], 0, 0, 0);
        }
        __syncthreads();
    }

    // epilogue — C/D layout: col = lane&15, row = quad*4 + reg   [verified m89/m91]
    #pragma unroll
    for (int i = 0; i < NI; i++) {
        #pragma unroll
        for (int j = 0; j < NJ; j++) {
            #pragma unroll
            for (int r = 0; r < 4; r++) {
                int row = m0 + wm + i*16 + quad*4 + r;
                int col = n0 + wn + j*16 + l16;
                float v = acc[i][j][r];
                if (EPI == 0) {
                    v += bias[col];
                    ((u16*)outp)[(size_t)row * N + col] = f2bf(v);
                } else if (EPI == 1) {
                    v += bias[col];
                    float gel = 0.5f * v * (1.f + erff(v * 0.70710678118654752f));
                    ((u16*)outp)[(size_t)row * N + col] = f2bf(gel);
                } else if (EPI == 2) {
                    v += bias[col] + res[(size_t)row * N + col];
                    ((float*)outp)[(size_t)row * N + col] = v;
                } else {
                    if (col < N) ((float*)outp)[(size_t)row * N + col] = v;
                }
            }
        }
    }
}

// ---------------------------------------------------------------------------
// V slice of fused qkv (BS, 768) bf16 -> Vt[b][h][d][s]  (PV B-frags contiguous in s)
__global__ __launch_bounds__(256) void vtrans_kernel(const u16* __restrict__ qkv,
                                                     u16* __restrict__ vt) {
    __shared__ u16 tile[32][33];
    int bh = blockIdx.z, b = bh >> 2, hh = bh & 3;
    int s0 = blockIdx.x * 32, d0 = blockIdx.y * 32;
    int tx = threadIdx.x, ty = threadIdx.y;          // block (32,8)
    #pragma unroll
    for (int i = 0; i < 4; i++)
        tile[ty + 8*i][tx] =
            qkv[(size_t)(b*SS + s0 + ty + 8*i) * QKVS + 2*DD + hh*HDIM + d0 + tx];
    __syncthreads();
    #pragma unroll
    for (int i = 0; i < 4; i++)
        vt[(size_t)(bh*HDIM + d0 + ty + 8*i) * SS + s0 + tx] = tile[tx][ty + 8*i];
}

// ---------------------------------------------------------------------------
// Flash-style causal attention over fused qkv. One workgroup = 64 q-rows of one
// (b,h); each wave owns 16 q-rows independently (NO barriers: P-tile LDS is
// per-wave private). K frags double-buffered in regs; V frags issued at the
// top of the iteration so their latency hides under QK^T + softmax.
__global__ __launch_bounds__(256) void attn_kernel(const u16* __restrict__ qkv,
                                                   const u16* __restrict__ vt,
                                                   u16* __restrict__ o) {
    const int tid = threadIdx.x;
    const int wid = tid >> 6, lane = tid & 63, quad = lane >> 4, l16 = lane & 15;
    const int bh = blockIdx.y, b = bh >> 2, hh = bh & 3;
    const int wq0 = blockIdx.x * 64 + wid * 16;

    __shared__ __align__(16) u16 plds[4][16 * 40];   // per-wave P tile (pad 32->40)

    const u16* qb = qkv + (size_t)b * SS * QKVS + hh * HDIM;        // Q segment
    const u16* kb = qb + DD;                                        // K segment
    const u16* vb = vt + (size_t)bh * HDIM * SS;

    // Q A-fragments (stay in regs): A[m=lane&15][k=quad*8+j], two 32-wide k steps
    bf16x8 qf0 = *(const bf16x8*)(qb + (size_t)(wq0 + l16) * QKVS + quad * 8);
    bf16x8 qf1 = *(const bf16x8*)(qb + (size_t)(wq0 + l16) * QKVS + 32 + quad * 8);

    f32x4 oacc0 = zero4(), oacc1 = zero4(), oacc2 = zero4(), oacc3 = zero4();
    float mst[4], lst[4];
    #pragma unroll
    for (int r = 0; r < 4; r++) { mst[r] = -1e30f; lst[r] = 0.f; }

    // per-wave tile count: rows wq0..wq0+15 need kv < wq0+16  ->  wq0/32 + 1
    const int nt = (wq0 >> 5) + 1;

    // prefetch K tile 0 into regs (double-buffered across iterations)
    const u16* krow = kb + (size_t)l16 * QKVS + quad * 8;
    bf16x8 kc0 = *(const bf16x8*)(krow);
    bf16x8 kc1 = *(const bf16x8*)(krow + 32);
    bf16x8 kc2 = *(const bf16x8*)(krow + (size_t)16 * QKVS);
    bf16x8 kc3 = *(const bf16x8*)(krow + (size_t)16 * QKVS + 32);

    for (int kt = 0; kt < nt; ++kt) {
        const int kv0 = kt * 32;

        // V frags for THIS tile, issued early — consumed only after softmax
        bf16x8 vf0 = *(const bf16x8*)(vb + (size_t)(     l16) * SS + kv0 + quad * 8);
        bf16x8 vf1 = *(const bf16x8*)(vb + (size_t)(16 + l16) * SS + kv0 + quad * 8);
        bf16x8 vf2 = *(const bf16x8*)(vb + (size_t)(32 + l16) * SS + kv0 + quad * 8);
        bf16x8 vf3 = *(const bf16x8*)(vb + (size_t)(48 + l16) * SS + kv0 + quad * 8);

        f32x4 sc0 = zero4(), sc1 = zero4();
        sc0 = __builtin_amdgcn_mfma_f32_16x16x32_bf16(qf0, kc0, sc0, 0, 0, 0);
        sc0 = __builtin_amdgcn_mfma_f32_16x16x32_bf16(qf1, kc1, sc0, 0, 0, 0);
        sc1 = __builtin_amdgcn_mfma_f32_16x16x32_bf16(qf0, kc2, sc1, 0, 0, 0);
        sc1 = __builtin_amdgcn_mfma_f32_16x16x32_bf16(qf1, kc3, sc1, 0, 0, 0);

        // prefetch NEXT K tile while softmax runs (wave-uniform branch)
        if (kt + 1 < nt) {
            const u16* kr = kb + (size_t)(kv0 + 32 + l16) * QKVS + quad * 8;
            kc0 = *(const bf16x8*)(kr);
            kc1 = *(const bf16x8*)(kr + 32);
            kc2 = *(const bf16x8*)(kr + (size_t)16 * QKVS);
            kc3 = *(const bf16x8*)(kr + (size_t)16 * QKVS + 32);
        }

        float p0[4], p1[4], mx[4];
        #pragma unroll
        for (int r = 0; r < 4; r++) {
            int qrow = wq0 + quad * 4 + r;
            float s0 = sc0[r] * 0.125f; if (kv0 + l16 > qrow)      s0 = -1e30f;
            float s1 = sc1[r] * 0.125f; if (kv0 + 16 + l16 > qrow) s1 = -1e30f;
            p0[r] = s0; p1[r] = s1;
            mx[r] = fmaxf(s0, s1);
        }
        #pragma unroll
        for (int m = 1; m < 16; m <<= 1) {
            #pragma unroll
            for (int r = 0; r < 4; r++) mx[r] = fmaxf(mx[r], __shfl_xor(mx[r], m));
        }
        float al[4], rsum[4];
        #pragma unroll
        for (int r = 0; r < 4; r++) {
            float mn = fmaxf(mst[r], mx[r]);
            al[r] = __expf(mst[r] - mn);
            mst[r] = mn;
            float e0 = __expf(p0[r] - mn);
            float e1 = __expf(p1[r] - mn);
            p0[r] = e0; p1[r] = e1;
            rsum[r] = e0 + e1;
        }
        #pragma unroll
        for (int m = 1; m < 16; m <<= 1) {
            #pragma unroll
            for (int r = 0; r < 4; r++) rsum[r] += __shfl_xor(rsum[r], m);
        }
        #pragma unroll
        for (int r = 0; r < 4; r++) {
            lst[r] = lst[r] * al[r] + rsum[r];
            oacc0[r] *= al[r]; oacc1[r] *= al[r];
            oacc2[r] *= al[r]; oacc3[r] *= al[r];
        }

        // P: C-layout -> per-wave LDS -> A-layout (intra-wave only; no barrier)
        u16* pw = &plds[wid][0];
        #pragma unroll
        for (int r = 0; r < 4; r++) {
            pw[(quad*4 + r) * 40 + l16]      = f2bf(p0[r]);
            pw[(quad*4 + r) * 40 + 16 + l16] = f2bf(p1[r]);
        }
        bf16x8 pf = *(const bf16x8*)(pw + l16 * 40 + quad * 8);
        oacc0 = __builtin_amdgcn_mfma_f32_16x16x32_bf16(pf, vf0, oacc0, 0, 0, 0);
        oacc1 = __builtin_amdgcn_mfma_f32_16x16x32_bf16(pf, vf1, oacc1, 0, 0, 0);
        oacc2 = __builtin_amdgcn_mfma_f32_16x16x32_bf16(pf, vf2, oacc2, 0, 0, 0);
        oacc3 = __builtin_amdgcn_mfma_f32_16x16x32_bf16(pf, vf3, oacc3, 0, 0, 0);
    }

    u16* ob = o + (size_t)b * SS * DD + hh * HDIM;
    #pragma unroll
    for (int r = 0; r < 4; r++) {
        const float inv = 1.f / lst[r];
        const size_t row = (size_t)(wq0 + quad*4 + r) * DD;
        ob[row +  0 + l16] = f2bf(oacc0[r] * inv);
        ob[row + 16 + l16] = f2bf(oacc1[r] * inv);
        ob[row + 32 + l16] = f2bf(oacc2[r] * inv);
        ob[row + 48 + l16] = f2bf(oacc3[r] * inv);
    }
}

// ---------------------------------------------------------------------------
extern "C" void kernel_launch(void* const* d_in, const int* in_sizes, int n_in,
                              void* d_out, int out_size, void* d_ws, size_t ws_size,
                              hipStream_t stream) {
    (void)in_sizes; (void)n_in; (void)out_size; (void)ws_size;
    const int*   ids  = (const int*)  d_in[0];
    const float* temb = (const float*)d_in[1];
    const float* pemb = (const float*)d_in[2];
    const float* Wq = (const float*)d_in[3];  const float* bq = (const float*)d_in[4];
    const float* Wk = (const float*)d_in[5];  const float* bk = (const float*)d_in[6];
    const float* Wv = (const float*)d_in[7];  const float* bv = (const float*)d_in[8];
    const float* Wo = (const float*)d_in[9];  const float* bo = (const float*)d_in[10];
    const float* ln1s = (const float*)d_in[11]; const float* ln1b = (const float*)d_in[12];
    const float* ln2s = (const float*)d_in[13]; const float* ln2b = (const float*)d_in[14];
    const float* W1 = (const float*)d_in[15]; const float* b1 = (const float*)d_in[16];
    const float* W2 = (const float*)d_in[17]; const float* b2 = (const float*)d_in[18];
    const float* lnfs = (const float*)d_in[19]; const float* lnfb = (const float*)d_in[20];
    float* out = (float*)d_out;

    char* ws = (char*)d_ws;
    auto alloc = [&](size_t bytes) -> char* {
        char* p = ws; ws += (bytes + 255) & ~(size_t)255; return p;
    };
    u16* tembb = (u16*)alloc((size_t)VV * DD * 2);        // bf16 tok_emb (lm_head B)
    u16* wqkvt = (u16*)alloc((size_t)LL * QKVS * DD * 2); // fused QKV^T bf16 weights
    u16* wot   = (u16*)alloc((size_t)LL * DD * DD * 2);
    u16* w1t   = (u16*)alloc((size_t)LL * DD * DFF * 2);
    u16* w2t   = (u16*)alloc((size_t)LL * DD * DFF * 2);
    float* bqkv= (float*)alloc((size_t)LL * QKVS * 4);    // fused QKV bias
    float* h   = (float*)alloc((size_t)BS * DD * 4);      // fp32 residual stream
    u16* nbuf  = (u16*)alloc((size_t)BS * DD * 2);        // LN output (bf16)
    u16* qkv   = (u16*)alloc((size_t)BS * QKVS * 2);      // fused QKV activations
    u16* vtb   = (u16*)alloc((size_t)BS * DD * 2);        // V transposed per (b,h)
    u16* obuf  = (u16*)alloc((size_t)BS * DD * 2);
    u16* f1    = (u16*)alloc((size_t)BS * DFF * 2);       // MLP hidden (bf16)

    // --- weight prep (ws is re-poisoned every call, so redo every call) ---
    cvt_kernel<<<(VV*DD/4 + 255)/256, 256, 0, stream>>>(temb, tembb, VV*DD/4);
    const dim3 wtB(32, 8);
    wtrans_kernel<<<dim3(DD/32, DD/32, LL), wtB, 0, stream>>>(
        Wq, wqkvt,             DD, DD, (size_t)QKVS * DD);
    wtrans_kernel<<<dim3(DD/32, DD/32, LL), wtB, 0, stream>>>(
        Wk, wqkvt + DD*DD,     DD, DD, (size_t)QKVS * DD);
    wtrans_kernel<<<dim3(DD/32, DD/32, LL), wtB, 0, stream>>>(
        Wv, wqkvt + 2*DD*DD,   DD, DD, (size_t)QKVS * DD);
    wtrans_kernel<<<dim3(DD/32, DD/32, LL), wtB, 0, stream>>>(
        Wo, wot, DD, DD, (size_t)DD * DD);
    wtrans_kernel<<<dim3(DFF/32, DD/32, LL), wtB, 0, stream>>>(
        W1, w1t, DD, DFF, (size_t)DD * DFF);
    wtrans_kernel<<<dim3(DD/32, DFF/32, LL), wtB, 0, stream>>>(
        W2, w2t, DFF, DD, (size_t)DD * DFF);
    bias_concat<<<(LL*QKVS + 255)/256, 256, 0, stream>>>(bq, bk, bv, bqkv);

    embed_kernel<<<BS*DD/4/256, 256, 0, stream>>>(ids, temb, pemb, h);

    const dim3 gQ(DD/64, BS/64);     // 64x64-tile GEMMs, N=256
    for (int l = 0; l < LL; l++) {
        ln_kernel<<<BS/4, 256, 0, stream>>>(h, ln1s + l*DD, ln1b + l*DD, nbuf);
        gemm_kernel<64,64,0><<<dim3(QKVS/64, BS/64), 256, 0, stream>>>(nbuf,
            wqkvt + (size_t)l*QKVS*DD, bqkv + (size_t)l*QKVS, nullptr, qkv,
            BS, QKVS, DD);
        vtrans_kernel<<<dim3(SS/32, HDIM/32, BB*HH), wtB, 0, stream>>>(qkv, vtb);
        attn_kernel<<<dim3(SS/64, BB*HH), 256, 0, stream>>>(qkv, vtb, obuf);
        gemm_kernel<64,64,2><<<gQ, 256, 0, stream>>>(obuf, wot + (size_t)l*DD*DD,
            bo + l*DD, h, h, BS, DD, DD);
        ln_kernel<<<BS/4, 256, 0, stream>>>(h, ln2s + l*DD, ln2b + l*DD, nbuf);
        gemm_kernel<128,128,1><<<dim3(DFF/128, BS/128), 256, 0, stream>>>(nbuf,
            w1t + (size_t)l*DD*DFF, b1 + l*DFF, nullptr, f1, BS, DFF, DD);
        gemm_kernel<64,64,2><<<gQ, 256, 0, stream>>>(f1, w2t + (size_t)l*DD*DFF,
            b2 + l*DD, h, h, BS, DD, DFF);
    }
    ln_kernel<<<BS/4, 256, 0, stream>>>(h, lnfs, lnfb, nbuf);
    gemm_kernel<128,128,3><<<dim3((VV + 127)/128, BS/128), 256, 0, stream>>>(nbuf,
        tembb, nullptr, nullptr, out, BS, VV, DD);
}